// Round 1
// baseline (99.891 us; speedup 1.0000x reference)
//
#include <hip/hip_runtime.h>

// N=524288 points, H=128 hidden, B=1024 batches.
// Strategy: s(x) and s'(x) are scalar->scalar smooth functions; tabulate on a
// 4096-entry grid over [-8,8] and Catmull-Rom interpolate per point.
// jac_i = s'(x_i)/count[b]; var[b] = sum(std^2 s'^2)/count^2 applied at finalize.

#define HH   128
#define NB   1024
#define TBL  4096
#define XMIN (-8.0f)
#define XMAX (8.0f)

__global__ __launch_bounds__(256) void zero_acc_kernel(float* __restrict__ acc) {
    int i = blockIdx.x * 256 + threadIdx.x;
    if (i < 3 * NB) acc[i] = 0.0f;
}

// grid = TBL/8 blocks x 256 threads. Each block computes 8 table entries.
// Thread layout: e = tid>>5 (entry 0..7), q = tid&31 owns j-columns [4q,4q+4).
// Forward z2 and backward v share each W2 LDS read (2 FMA per element read).
__global__ __launch_bounds__(256) void build_table_kernel(
    const float* __restrict__ W1, const float* __restrict__ b1,
    const float* __restrict__ W2, const float* __restrict__ b2,
    const float* __restrict__ W3, const float* __restrict__ b3,
    float* __restrict__ s_tab, float* __restrict__ d_tab)
{
    __shared__ float W2s[HH * HH];   // 64 KB, row-major [k][j]
    __shared__ float h1s[8][HH];
    __shared__ float us[8][HH];
    const int tid = threadIdx.x;
    {
        const float4* src = (const float4*)W2;
        float4* dst = (float4*)W2s;
        for (int i = tid; i < HH * HH / 4; i += 256) dst[i] = src[i];
    }
    const int e = tid >> 5;
    const int q = tid & 31;
    const float dxt = (XMAX - XMIN) / (float)(TBL - 1);
    const int eg = blockIdx.x * 8 + e;
    const float x = XMIN + (float)eg * dxt;
    #pragma unroll
    for (int kk = 0; kk < 4; ++kk) {
        int k = q * 4 + kk;
        float w1 = W1[k];
        float h = tanhf(fmaf(x, w1, b1[k]));
        h1s[e][k] = h;
        us[e][k] = w1 * (1.0f - h * h);   // u_k = W1_k (1 - h1_k^2)
    }
    __syncthreads();

    float accz[4] = {0.f, 0.f, 0.f, 0.f};
    float accv[4] = {0.f, 0.f, 0.f, 0.f};
    const int jb = q * 4;
    #pragma unroll 2
    for (int k = 0; k < HH; k += 4) {
        float4 h4 = *(const float4*)&h1s[e][k];  // broadcast b128
        float4 u4 = *(const float4*)&us[e][k];   // broadcast b128
        float hk[4] = {h4.x, h4.y, h4.z, h4.w};
        float uk[4] = {u4.x, u4.y, u4.z, u4.w};
        #pragma unroll
        for (int kk = 0; kk < 4; ++kk) {
            float4 w = *(const float4*)&W2s[(k + kk) * HH + jb];
            float h = hk[kk], u = uk[kk];
            accz[0] = fmaf(h, w.x, accz[0]); accv[0] = fmaf(u, w.x, accv[0]);
            accz[1] = fmaf(h, w.y, accz[1]); accv[1] = fmaf(u, w.y, accv[1]);
            accz[2] = fmaf(h, w.z, accz[2]); accv[2] = fmaf(u, w.z, accv[2]);
            accz[3] = fmaf(h, w.w, accz[3]); accv[3] = fmaf(u, w.w, accv[3]);
        }
    }
    float ps = 0.f, pd = 0.f;
    #pragma unroll
    for (int i = 0; i < 4; ++i) {
        int j = jb + i;
        float h2 = tanhf(accz[i] + b2[j]);
        float w3 = W3[j];
        ps = fmaf(w3, h2, ps);                        // s partial
        pd = fmaf((1.0f - h2 * h2) * w3, accv[i], pd); // s' partial
    }
    #pragma unroll
    for (int o = 16; o > 0; o >>= 1) {
        ps += __shfl_down(ps, o, 32);
        pd += __shfl_down(pd, o, 32);
    }
    if (q == 0) {
        s_tab[eg] = ps + b3[0];
        d_tab[eg] = pd;
    }
}

__device__ __forceinline__ float catmull(const float* __restrict__ tab, int i0, float t) {
    float fm = tab[i0 - 1], f0 = tab[i0], f1 = tab[i0 + 1], f2 = tab[i0 + 2];
    float a1 = 0.5f * (f1 - fm);
    float a2 = fm - 2.5f * f0 + 2.0f * f1 - 0.5f * f2;
    float a3 = 1.5f * (f0 - f1) + 0.5f * (f2 - fm);
    return fmaf(fmaf(fmaf(a3, t, a2), t, a1), t, f0);
}

// grid = 256 blocks x 256 threads, grid-stride over N. LDS per-batch bins,
// one flush of global atomics per block (skip empty bins).
__global__ __launch_bounds__(256) void main_pass_kernel(
    const float2* __restrict__ feat, const int* __restrict__ ids,
    const float* __restrict__ s_tab, const float* __restrict__ d_tab,
    float* __restrict__ acc, int n)
{
    __shared__ float bs[NB];
    __shared__ float bv[NB];
    __shared__ float bc[NB];
    const int tid = threadIdx.x;
    for (int i = tid; i < NB; i += 256) { bs[i] = 0.f; bv[i] = 0.f; bc[i] = 0.f; }
    __syncthreads();
    const float inv_dx = (float)(TBL - 1) / (XMAX - XMIN);
    const int stride = gridDim.x * 256;
    for (int i = blockIdx.x * 256 + tid; i < n; i += stride) {
        float2 f = feat[i];
        int b = ids[i];
        float x = fminf(fmaxf(f.x, XMIN), XMAX);
        float u = (x - XMIN) * inv_dx;
        int i0 = (int)u;
        i0 = min(max(i0, 1), TBL - 3);
        float t = u - (float)i0;
        float s = catmull(s_tab, i0, t);
        float d = catmull(d_tab, i0, t);
        atomicAdd(&bs[b], s);
        atomicAdd(&bv[b], f.y * f.y * d * d);
        atomicAdd(&bc[b], 1.0f);
    }
    __syncthreads();
    for (int b = tid; b < NB; b += 256) {
        float c = bc[b];
        if (c != 0.f) {
            atomicAdd(&acc[b], bs[b]);
            atomicAdd(&acc[NB + b], bv[b]);
            atomicAdd(&acc[2 * NB + b], c);
        }
    }
}

__global__ __launch_bounds__(256) void finalize_kernel(const float* __restrict__ acc,
                                                       float* __restrict__ out) {
    int b = blockIdx.x * 256 + threadIdx.x;
    if (b < NB) {
        float c = fmaxf(acc[2 * NB + b], 1.0f);
        out[2 * b]     = acc[b] / c;          // pred_mean
        out[2 * b + 1] = acc[NB + b] / (c * c); // pred_sdp_var (jac = s'/count)
    }
}

extern "C" void kernel_launch(void* const* d_in, const int* in_sizes, int n_in,
                              void* d_out, int out_size, void* d_ws, size_t ws_size,
                              hipStream_t stream) {
    const float* feat = (const float*)d_in[0];
    const int*   ids  = (const int*)d_in[1];
    const float* W1   = (const float*)d_in[2];
    const float* b1   = (const float*)d_in[3];
    const float* W2   = (const float*)d_in[4];
    const float* b2   = (const float*)d_in[5];
    const float* W3   = (const float*)d_in[6];
    const float* b3   = (const float*)d_in[7];
    const int n = in_sizes[1];   // number of points (batch_ids length)

    float* s_tab = (float*)d_ws;          // TBL floats
    float* d_tab = s_tab + TBL;           // TBL floats
    float* acc   = d_tab + TBL;           // 3*NB floats (sum_s, sum_v, count)

    zero_acc_kernel<<<(3 * NB + 255) / 256, 256, 0, stream>>>(acc);
    build_table_kernel<<<TBL / 8, 256, 0, stream>>>(W1, b1, W2, b2, W3, b3, s_tab, d_tab);
    main_pass_kernel<<<256, 256, 0, stream>>>((const float2*)feat, ids, s_tab, d_tab, acc, n);
    finalize_kernel<<<(NB + 255) / 256, 256, 0, stream>>>(acc, (float*)d_out);
}